// Round 8
// baseline (431.641 us; speedup 1.0000x reference)
//
#include <hip/hip_runtime.h>
#include <hip/hip_bf16.h>
#include <math.h>

#define N_TOK 2048
#define DIM   1024
#define FF    2048
#define NEXP  8
#define NSLOT (N_TOK * 2)
#define NCVT  12288   // 3 matrices x 8 experts x 512 (64x64) tiles

typedef __attribute__((ext_vector_type(8))) short short8;
typedef __attribute__((ext_vector_type(4))) float f32x4;
typedef _Float16 half_t;
typedef __attribute__((ext_vector_type(4))) _Float16 h16x4;

__device__ __forceinline__ unsigned short f2bf(float f) {
    unsigned int u = __float_as_uint(f);
    u += 0x7FFFu + ((u >> 16) & 1u);   // round-to-nearest-even
    return (unsigned short)(u >> 16);
}

// async global->LDS 16B: LDS dst is wave-uniform base + lane*16
#define GLOAD_LDS16(g, l) \
    __builtin_amdgcn_global_load_lds((const __attribute__((address_space(1))) unsigned int*)(g), \
                                     (__attribute__((address_space(3))) unsigned int*)(l), 16, 0, 0)

// ---------------- prep: weight cvt -> blocked LDS-image + router (+assign) ----
// Blocked image layout: block (e,ft,kt) is the exact 64f x 32k LDS image the
// GEMM stages per K-step, pre-XOR-swizzled, stored contiguously.  W_out:
// 128d x 32k blocks.  Tile decode puts the f/d tile FASTEST so consecutive
// blocks stream complete source rows (DRAM page locality); writes stay
// 8KB-contiguous per block.  LDS stride 68 ushorts: store bases 8m mod 32
// (4-way) and read bases (2r+4c) mod 32 (2-way, free).
__global__ __launch_bounds__(256) void k_prep(
        const float* __restrict__ x, const float* __restrict__ Wg,
        const float* __restrict__ Win, const float* __restrict__ Wsc,
        const float* __restrict__ Wout,
        unsigned short* __restrict__ wt_h, unsigned short* __restrict__ wt_s,
        unsigned short* __restrict__ wt_o,
        int* __restrict__ hdr, int* __restrict__ tok_e,
        float* __restrict__ tok_w, int* __restrict__ tok_slot,
        unsigned short* __restrict__ xg, int mode) {
    __shared__ unsigned short sh[64][68];    // [f/d][k]; 136B rows, 8B-aligned
    int gid = blockIdx.x;
    int t = threadIdx.x;

    if (gid < NCVT) {
        int which = gid >> 12;               // 4096 blocks per matrix
        int local = gid & 4095;
        int e = local >> 9;                  // 512 tiles per expert
        int rem = local & 511;
        int rl = t >> 4, cl = (t & 15) * 4;  // load: 16 lanes/row, float4
        if (which < 2) {
            int ft = rem & 31, kg = rem >> 5;        // ft FASTEST: row streaming
            const float* S = ((which == 0) ? Win : Wsc) + (size_t)e * DIM * FF
                             + (size_t)(kg * 64) * FF + ft * 64;
            unsigned short* D = ((which == 0) ? wt_h : wt_s)
                                + (((size_t)e * 32 + ft) * 32 + kg * 2) * 2048;
#pragma unroll
            for (int p = 0; p < 4; ++p) {
                int k = p * 16 + rl;
                float4 v = *(const float4*)(S + (size_t)k * FF + cl);
                sh[cl + 0][k] = f2bf(v.x);
                sh[cl + 1][k] = f2bf(v.y);
                sh[cl + 2][k] = f2bf(v.z);
                sh[cl + 3][k] = f2bf(v.w);
            }
            __syncthreads();
            int r = t >> 2, c = t & 3;
#pragma unroll
            for (int p2 = 0; p2 < 2; ++p2) {         // two 4KB image blocks
                int ks = p2 * 32 + ((c ^ ((r >> 1) & 3)) * 8);
                uint2 lo = *(const uint2*)&sh[r][ks];
                uint2 hi = *(const uint2*)&sh[r][ks + 4];
                *(uint4*)(D + (size_t)p2 * 2048 + t * 8) =
                    make_uint4(lo.x, lo.y, hi.x, hi.y);
            }
        } else {
            int dg = rem & 15, kg = rem >> 4;        // dg FASTEST: row streaming
            const float* S = Wout + (size_t)e * DIM * FF
                             + (size_t)(kg * 64) * DIM + dg * 64;
            int dt = dg >> 1, o = (dg & 1) * 64;     // half of a 128d block
            unsigned short* D = wt_o + (((size_t)e * 8 + dt) * 64 + kg * 2) * 4096
                                + o * 32;
#pragma unroll
            for (int p = 0; p < 4; ++p) {
                int k = p * 16 + rl;
                float4 v = *(const float4*)(S + (size_t)k * DIM + cl);
                sh[cl + 0][k] = f2bf(v.x);
                sh[cl + 1][k] = f2bf(v.y);
                sh[cl + 2][k] = f2bf(v.z);
                sh[cl + 3][k] = f2bf(v.w);
            }
            __syncthreads();
            int r = t >> 2, c = t & 3;               // r is local d (o+r global)
#pragma unroll
            for (int p2 = 0; p2 < 2; ++p2) {
                int ks = p2 * 32 + ((c ^ ((r >> 1) & 3)) * 8);
                uint2 lo = *(const uint2*)&sh[r][ks];
                uint2 hi = *(const uint2*)&sh[r][ks + 4];
                *(uint4*)(D + (size_t)p2 * 4096 + t * 8) =
                    make_uint4(lo.x, lo.y, hi.x, hi.y);
            }
        }
        return;
    }

    // ------- router (+assign in mode 1) -------
    int rblk = gid - NCVT;
    int wave = t >> 6, lane = t & 63;
    int tok = rblk * 4 + wave;
    if (mode && rblk == 0 && t < NEXP) hdr[16 + t] = t * N_TOK;  // fixed bases

    float acc[NEXP];
#pragma unroll
    for (int e = 0; e < NEXP; ++e) acc[e] = 0.f;
    const float* xr = x + (size_t)tok * DIM;
    for (int d = lane; d < DIM; d += 64) {
        float xv = xr[d];
        const float* wr = Wg + d * NEXP;
#pragma unroll
        for (int e = 0; e < NEXP; ++e) acc[e] += xv * wr[e];
    }
#pragma unroll
    for (int off = 32; off > 0; off >>= 1) {
#pragma unroll
        for (int e = 0; e < NEXP; ++e) acc[e] += __shfl_down(acc[e], off);
    }
    int s0 = 0, s1 = 0;
    if (lane == 0) {
        int e0 = 0;
#pragma unroll
        for (int e = 1; e < NEXP; ++e) if (acc[e] > acc[e0]) e0 = e;
        int e1 = -1;
#pragma unroll
        for (int e = 0; e < NEXP; ++e) {
            if (e == e0) continue;
            if (e1 < 0 || acc[e] > acc[e1]) e1 = e;
        }
        float w0 = 1.f / (1.f + expf(acc[e1] - acc[e0]));
        tok_e[2 * tok] = e0; tok_e[2 * tok + 1] = e1;
        tok_w[2 * tok] = w0; tok_w[2 * tok + 1] = 1.f - w0;
        if (mode) {
            int p0 = atomicAdd(&hdr[e0], 1);
            int p1 = atomicAdd(&hdr[e1], 1);
            s0 = e0 * N_TOK + p0; s1 = e1 * N_TOK + p1;
            tok_slot[2 * tok] = s0; tok_slot[2 * tok + 1] = s1;
        } else {
            atomicAdd(&hdr[e0], 1);
            atomicAdd(&hdr[e1], 1);
        }
    }
    if (mode) {       // fused assign: gather this token's row -> both slabs
        s0 = __shfl(s0, 0); s1 = __shfl(s1, 0);
        const float4* xv4 = (const float4*)xr;
#pragma unroll
        for (int j = 0; j < 4; ++j) {
            float4 v = xv4[lane + j * 64];
            ushort4 b;
            b.x = f2bf(v.x); b.y = f2bf(v.y); b.z = f2bf(v.z); b.w = f2bf(v.w);
            ((ushort4*)(xg + (size_t)s0 * DIM))[lane + j * 64] = b;
            ((ushort4*)(xg + (size_t)s1 * DIM))[lane + j * 64] = b;
        }
    }
}

// ---------------- scan (compact mode only) ------------------------------------
__global__ void k_scan(int* hdr) {
    if (threadIdx.x == 0 && blockIdx.x == 0) {
        int s = 0;
        for (int e = 0; e < NEXP; ++e) {
            hdr[16 + e] = s;
            hdr[8 + e]  = s;
            s += hdr[e];
        }
        hdr[24] = s;
    }
}

// ---------------- assign (compact mode only) ----------------------------------
__global__ __launch_bounds__(256) void k_assign(const float* __restrict__ x,
        int* __restrict__ hdr, const int* __restrict__ tok_e,
        int* __restrict__ tok_slot, unsigned short* __restrict__ xg) {
    __shared__ int sh[2];
    int t = blockIdx.x;
    if (threadIdx.x == 0) {
        int e0 = tok_e[2 * t], e1 = tok_e[2 * t + 1];
        int p0 = atomicAdd(&hdr[8 + e0], 1);
        int p1 = atomicAdd(&hdr[8 + e1], 1);
        tok_slot[2 * t] = p0; tok_slot[2 * t + 1] = p1;
        sh[0] = p0; sh[1] = p1;
    }
    __syncthreads();
    int s0 = sh[0], s1 = sh[1];
    const float4* xr = (const float4*)(x + (size_t)t * DIM);
    float4 v = xr[threadIdx.x];
    ushort4 b;
    b.x = f2bf(v.x); b.y = f2bf(v.y); b.z = f2bf(v.z); b.w = f2bf(v.w);
    ((ushort4*)(xg + (size_t)s0 * DIM))[threadIdx.x] = b;
    ((ushort4*)(xg + (size_t)s1 * DIM))[threadIdx.x] = b;
}

// ---------------- expert dual-GEMM h & s + exact GELU -> inner (bf16) --------
// tile 128 x 64F, K-step 32, 4 waves 2x2, acc=64 VGPR -> 4 blocks/CU.
// Dbuf stage-ahead, ONE barrier/step.  B from blocked image (linear DMA src).
__global__ __launch_bounds__(256, 4) void k_expert_hs(
        const unsigned short* __restrict__ xg,
        const unsigned short* __restrict__ Wth,
        const unsigned short* __restrict__ Wts,
        const float* __restrict__ b_in, const float* __restrict__ b_sc,
        const int* __restrict__ hdr, unsigned short* __restrict__ inner) {
    int e = blockIdx.z;
    int cnt = hdr[e];
    int mtile = blockIdx.y;
    if (mtile * 128 >= cnt) return;
    int base = hdr[16 + e];
    int f0 = blockIdx.x * 64;

    __shared__ unsigned short As[2 * 128 * 32];  // dbuf [row][k] 64B rows
    __shared__ unsigned short Bh[2 * 64 * 32];
    __shared__ unsigned short Bs[2 * 64 * 32];

    int tid = threadIdx.x;
    int wave = tid >> 6, lane = tid & 63;
    int lr = lane & 15, lq = lane >> 4;
    int wm = (wave >> 1) * 64, wf = (wave & 1) * 32;

    f32x4 acch[4][2], accs[4][2];
#pragma unroll
    for (int mi = 0; mi < 4; ++mi)
#pragma unroll
        for (int fi = 0; fi < 2; ++fi) {
            acch[mi][fi] = (f32x4){0.f, 0.f, 0.f, 0.f};
            accs[mi][fi] = (f32x4){0.f, 0.f, 0.f, 0.f};
        }

    int swzc = (lane & 3) ^ ((lane >> 3) & 3);
    int goff = (lane >> 2) * DIM + swzc * 8;           // A: ushort units, ld=DIM
    int rdo = lr * 32 + (lq ^ ((lr >> 1) & 3)) * 8;    // swizzled read offset

    const unsigned short* Abase = xg  + (size_t)(base + mtile * 128) * DIM + goff;
    // blocked B: per (e,ft) panel is 32 sequential 2048-short blocks
    const unsigned short* Hp = Wth + (((size_t)e * 32 + (f0 >> 6)) * 32) * 2048
                               + wave * 512 + lane * 8;
    const unsigned short* Sp = Wts + (((size_t)e * 32 + (f0 >> 6)) * 32) * 2048
                               + wave * 512 + lane * 8;
    int pa0 = wave * 16, pa1 = 64 + wave * 16;
    int wb = wave * 512;

    GLOAD_LDS16(Abase + (size_t)pa0 * DIM, &As[pa0 * 32]);
    GLOAD_LDS16(Abase + (size_t)pa1 * DIM, &As[pa1 * 32]);
    GLOAD_LDS16(Hp, &Bh[wb]);
    GLOAD_LDS16(Sp, &Bs[wb]);
    __syncthreads();

    const int NSTEP = DIM / 32;
    for (int t = 0; t < NSTEP; ++t) {
        int coA = (t & 1) * (128 * 32), coB = (t & 1) * (64 * 32);
        if (t + 1 < NSTEP) {                 // stage next tile first (overlap)
            int noA = ((t & 1) ^ 1) * (128 * 32), noB = ((t & 1) ^ 1) * (64 * 32);
            int k1 = (t + 1) * 32;
            GLOAD_LDS16(Abase + (size_t)pa0 * DIM + k1, &As[noA + pa0 * 32]);
            GLOAD_LDS16(Abase + (size_t)pa1 * DIM + k1, &As[noA + pa1 * 32]);
            GLOAD_LDS16(Hp + (size_t)(t + 1) * 2048, &Bh[noB + wb]);
            GLOAD_LDS16(Sp + (size_t)(t + 1) * 2048, &Bs[noB + wb]);
        }

        short8 af[4], bhf[2], bsf[2];
#pragma unroll
        for (int mi = 0; mi < 4; ++mi)
            af[mi] = *(const short8*)&As[coA + (wm + mi * 16) * 32 + rdo];
#pragma unroll
        for (int fi = 0; fi < 2; ++fi) {
            bhf[fi] = *(const short8*)&Bh[coB + (wf + fi * 16) * 32 + rdo];
            bsf[fi] = *(const short8*)&Bs[coB + (wf + fi * 16) * 32 + rdo];
        }
#pragma unroll
        for (int mi = 0; mi < 4; ++mi)
#pragma unroll
            for (int fi = 0; fi < 2; ++fi) {
                acch[mi][fi] = __builtin_amdgcn_mfma_f32_16x16x32_bf16(
                    af[mi], bhf[fi], acch[mi][fi], 0, 0, 0);
                accs[mi][fi] = __builtin_amdgcn_mfma_f32_16x16x32_bf16(
                    af[mi], bsf[fi], accs[mi][fi], 0, 0, 0);
            }
        __syncthreads();   // readers done + next-tile DMA drained (vmcnt 0)
    }

#pragma unroll
    for (int fi = 0; fi < 2; ++fi) {
        int f = f0 + wf + fi * 16 + lr;
        float bi = b_in[e * FF + f];
        float bs2 = b_sc[e * FF + f];
#pragma unroll
        for (int mi = 0; mi < 4; ++mi) {
#pragma unroll
            for (int r = 0; r < 4; ++r) {
                int rl = wm + mi * 16 + lq * 4 + r;
                int grow = mtile * 128 + rl;
                if (grow < cnt) {
                    float h = acch[mi][fi][r] + bi;
                    float s = accs[mi][fi][r] + bs2;
                    float g = 0.5f * h * (1.f + erff(h * 0.70710678f));
                    inner[(size_t)(base + grow) * FF + f] = f2bf(g * s);
                }
            }
        }
    }
}

// ---------------- expert out-GEMM, split-K=2, fp16 partials -------------------
// tile 128 x 128D, 4 waves 2x2, acc=64 VGPR -> 4 blocks/CU.  Blocked B image.
__global__ __launch_bounds__(256, 4) void k_expert_out(
        const unsigned short* __restrict__ inner,
        const unsigned short* __restrict__ Wto,
        const int* __restrict__ hdr, half_t* __restrict__ pbuf, int pstride) {
    int e = blockIdx.z & 7;
    int ks = blockIdx.z >> 3;
    int cnt = hdr[e];
    int mtile = blockIdx.y;
    if (mtile * 128 >= cnt) return;
    int base = hdr[16 + e];
    int d0 = blockIdx.x * 128;

    __shared__ unsigned short As[2 * 128 * 32];  // dbuf [row][k]
    __shared__ unsigned short Bt[2 * 128 * 32];  // dbuf [d][k] image

    int tid = threadIdx.x;
    int wave = tid >> 6, lane = tid & 63;
    int lr = lane & 15, lq = lane >> 4;
    int wm = (wave >> 1) * 64, wn = (wave & 1) * 64;

    f32x4 acc[4][4];
#pragma unroll
    for (int mi = 0; mi < 4; ++mi)
#pragma unroll
        for (int ni = 0; ni < 4; ++ni) acc[mi][ni] = (f32x4){0.f, 0.f, 0.f, 0.f};

    int swzc = (lane & 3) ^ ((lane >> 3) & 3);
    int goff = (lane >> 2) * FF + swzc * 8;            // A: ld = FF
    int rdo = lr * 32 + (lq ^ ((lr >> 1) & 3)) * 8;

    const unsigned short* Abase = inner + (size_t)(base + mtile * 128) * FF + goff;
    // blocked B: per (e,dt) panel is 64 sequential 4096-short blocks; start at ks*32
    const unsigned short* Bp = Wto + ((((size_t)e * 8 + (d0 >> 7)) * 64 + (size_t)ks * 32)) * 4096
                               + wave * 512 + lane * 8;
    int pa0 = wave * 16, pa1 = 64 + wave * 16;
    int wb = wave * 512;

    int kbeg = ks * (FF / 2);

    GLOAD_LDS16(Abase + (size_t)pa0 * FF + kbeg, &As[pa0 * 32]);
    GLOAD_LDS16(Abase + (size_t)pa1 * FF + kbeg, &As[pa1 * 32]);
    GLOAD_LDS16(Bp, &Bt[wb]);
    GLOAD_LDS16(Bp + 2048, &Bt[2048 + wb]);
    __syncthreads();

    const int NSTEP = (FF / 2) / 32;
    for (int t = 0; t < NSTEP; ++t) {
        int co = (t & 1) * (128 * 32);
        if (t + 1 < NSTEP) {
            int no = ((t & 1) ^ 1) * (128 * 32);
            int k1 = kbeg + (t + 1) * 32;
            GLOAD_LDS16(Abase + (size_t)pa0 * FF + k1, &As[no + pa0 * 32]);
            GLOAD_LDS16(Abase + (size_t)pa1 * FF + k1, &As[no + pa1 * 32]);
            GLOAD_LDS16(Bp + (size_t)(t + 1) * 4096, &Bt[no + wb]);
            GLOAD_LDS16(Bp + (size_t)(t + 1) * 4096 + 2048, &Bt[no + 2048 + wb]);
        }

        short8 af[4], bfm[4];
#pragma unroll
        for (int mi = 0; mi < 4; ++mi)
            af[mi] = *(const short8*)&As[co + (wm + mi * 16) * 32 + rdo];
#pragma unroll
        for (int ni = 0; ni < 4; ++ni)
            bfm[ni] = *(const short8*)&Bt[co + (wn + ni * 16) * 32 + rdo];
#pragma unroll
        for (int mi = 0; mi < 4; ++mi)
#pragma unroll
            for (int ni = 0; ni < 4; ++ni)
                acc[mi][ni] = __builtin_amdgcn_mfma_f32_16x16x32_bf16(
                    af[mi], bfm[ni], acc[mi][ni], 0, 0, 0);
        __syncthreads();
    }

    half_t* P = pbuf + (size_t)ks * pstride * DIM;
#pragma unroll
    for (int ni = 0; ni < 4; ++ni) {
        int d = d0 + wn + ni * 16 + lr;
#pragma unroll
        for (int mi = 0; mi < 4; ++mi) {
#pragma unroll
            for (int r = 0; r < 4; ++r) {
                int rl = wm + mi * 16 + lq * 4 + r;
                int grow = mtile * 128 + rl;
                if (grow < cnt)
                    P[(size_t)(base + grow) * DIM + d] = (half_t)acc[mi][ni][r];
            }
        }
    }
}

// ---------------- combine: out = w0*(p0+p1+b[e0]) + w1*(...) ------------------
__global__ __launch_bounds__(256) void k_combine(const half_t* __restrict__ pbuf,
        const int* __restrict__ tok_slot, const int* __restrict__ tok_e,
        const float* __restrict__ tok_w, const float* __restrict__ b_out,
        float* __restrict__ out, int pstride) {
    int t = blockIdx.x;
    int d = threadIdx.x * 4;
    int s0 = tok_slot[2 * t], s1 = tok_slot[2 * t + 1];
    int e0 = tok_e[2 * t], e1 = tok_e[2 * t + 1];
    float w0 = tok_w[2 * t], w1 = tok_w[2 * t + 1];
    const half_t* pA = pbuf;
    const half_t* pB = pbuf + (size_t)pstride * DIM;
    h16x4 a0 = *(const h16x4*)&pA[(size_t)s0 * DIM + d];
    h16x4 a1 = *(const h16x4*)&pB[(size_t)s0 * DIM + d];
    h16x4 c0 = *(const h16x4*)&pA[(size_t)s1 * DIM + d];
    h16x4 c1 = *(const h16x4*)&pB[(size_t)s1 * DIM + d];
    float4 b0 = *(const float4*)&b_out[e0 * DIM + d];
    float4 b1 = *(const float4*)&b_out[e1 * DIM + d];
    float4 r;
    r.x = w0 * ((float)a0.x + (float)a1.x + b0.x) + w1 * ((float)c0.x + (float)c1.x + b1.x);
    r.y = w0 * ((float)a0.y + (float)a1.y + b0.y) + w1 * ((float)c0.y + (float)c1.y + b1.y);
    r.z = w0 * ((float)a0.z + (float)a1.z + b0.z) + w1 * ((float)c0.z + (float)c1.z + b1.z);
    r.w = w0 * ((float)a0.w + (float)a1.w + b0.w) + w1 * ((float)c0.w + (float)c1.w + b1.w);
    *(float4*)&out[(size_t)t * DIM + d] = r;
}

extern "C" void kernel_launch(void* const* d_in, const int* in_sizes, int n_in,
                              void* d_out, int out_size, void* d_ws, size_t ws_size,
                              hipStream_t stream) {
    (void)in_sizes; (void)n_in; (void)out_size;
    const float* x    = (const float*)d_in[0];
    const float* Wg   = (const float*)d_in[1];
    const float* Win  = (const float*)d_in[2];
    const float* b_in = (const float*)d_in[3];
    const float* Wsc  = (const float*)d_in[4];
    const float* b_sc = (const float*)d_in[5];
    const float* Wout = (const float*)d_in[6];
    const float* b_out= (const float*)d_in[7];
    float* out = (float*)d_out;

    char* ws = (char*)d_ws;
    int*   hdr      = (int*)ws;
    int*   tok_e    = (int*)(ws + 256);
    float* tok_w    = (float*)(ws + 16640);
    int*   tok_slot = (int*)(ws + 33024);

    // big mode: fixed per-expert slabs (base_e = e*2048) -> no scan/assign
    const size_t BIG_NEED = 65792ULL + (32ULL + 64 + 64 + 96) * 1024 * 1024;
    int big = (ws_size >= BIG_NEED) ? 1 : 0;

    unsigned short *xg, *inner, *wt_h, *wt_s, *wt_o;
    half_t* pbuf;
    int slab;
    if (big) {
        xg    = (unsigned short*)(ws + 65792);                       // 32 MB
        inner = (unsigned short*)(ws + 65792 + 33554432);            // 64 MB
        pbuf  = (half_t*)(ws + 65792 + 33554432 + 67108864);         // 64 MB
        wt_h  = (unsigned short*)(ws + 65792 + 33554432 + 67108864 + 67108864);
        wt_s  = wt_h + (size_t)NEXP * FF * DIM;                      // +32 MB
        wt_o  = wt_s + (size_t)NEXP * FF * DIM;                      // +32 MB
        slab  = NEXP * N_TOK;                                        // 16384
    } else {
        xg    = (unsigned short*)(ws + 65792);                       // 8 MB
        inner = (unsigned short*)(ws + 65792 + 8388608);             // 16 MB
        pbuf  = (half_t*)(ws + 65792 + 8388608 + 16777216);          // 16 MB
        wt_h  = (unsigned short*)(ws + 65792 + 8388608 + 16777216 + 16777216);
        wt_s  = wt_h + (size_t)NEXP * FF * DIM;                      // +32 MB
        wt_o  = wt_s + (size_t)NEXP * FF * DIM;                      // +32 MB
        slab  = NSLOT;                                               // 4096
    }

    hipMemsetAsync(hdr, 0, 256, stream);
    k_prep<<<dim3(NCVT + N_TOK / 4), dim3(256), 0, stream>>>(
        x, Wg, Win, Wsc, Wout, wt_h, wt_s, wt_o,
        hdr, tok_e, tok_w, tok_slot, xg, big);
    if (!big) {
        k_scan<<<dim3(1), dim3(64), 0, stream>>>(hdr);
        k_assign<<<dim3(N_TOK), dim3(256), 0, stream>>>(x, hdr, tok_e, tok_slot, xg);
    }
    k_expert_hs<<<dim3(FF / 64, 16, NEXP), dim3(256), 0, stream>>>(
        xg, wt_h, wt_s, b_in, b_sc, hdr, inner);
    k_expert_out<<<dim3(DIM / 128, 16, NEXP * 2), dim3(256), 0, stream>>>(
        inner, wt_o, hdr, pbuf, slab);
    k_combine<<<dim3(N_TOK), dim3(256), 0, stream>>>(
        pbuf, tok_slot, tok_e, tok_w, b_out, out, slab);
}

// Round 9
// 413.722 us; speedup vs baseline: 1.0433x; 1.0433x over previous
//
#include <hip/hip_runtime.h>
#include <hip/hip_bf16.h>
#include <math.h>

#define N_TOK 2048
#define DIM   1024
#define FF    2048
#define NEXP  8
#define NSLOT (N_TOK * 2)
#define NRTR  (N_TOK / 4)   // 512 router blocks, FIRST in grid (latency-hidden)
#define NCVT  12288         // 3 matrices x 8 experts x 512 (64x64) tiles

typedef __attribute__((ext_vector_type(8))) short short8;
typedef __attribute__((ext_vector_type(4))) float f32x4;
typedef _Float16 half_t;
typedef __attribute__((ext_vector_type(4))) _Float16 h16x4;

__device__ __forceinline__ unsigned short f2bf(float f) {
    unsigned int u = __float_as_uint(f);
    u += 0x7FFFu + ((u >> 16) & 1u);   // round-to-nearest-even
    return (unsigned short)(u >> 16);
}

// async global->LDS 16B: LDS dst is wave-uniform base + lane*16
#define GLOAD_LDS16(g, l) \
    __builtin_amdgcn_global_load_lds((const __attribute__((address_space(1))) unsigned int*)(g), \
                                     (__attribute__((address_space(3))) unsigned int*)(l), 16, 0, 0)

// ---------------- prep: router (+assign) FIRST, then weight cvt ---------------
// Router blocks are gid < NRTR so they dispatch EARLY and their gather/scatter
// latency hides under the cvt blocks' BW-bound streaming (r5-r8 ran them as a
// post-cvt tail: +40us).  Cvt: block (e,ft,kt) emits the exact pre-swizzled
// 64x32 LDS image the GEMMs stage per K-step (8KB sequential writes).
__global__ __launch_bounds__(256) void k_prep(
        const float* __restrict__ x, const float* __restrict__ Wg,
        const float* __restrict__ Win, const float* __restrict__ Wsc,
        const float* __restrict__ Wout,
        unsigned short* __restrict__ wt_h, unsigned short* __restrict__ wt_s,
        unsigned short* __restrict__ wt_o,
        int* __restrict__ hdr, int* __restrict__ tok_e,
        float* __restrict__ tok_w, int* __restrict__ tok_slot,
        unsigned short* __restrict__ xg, int mode) {
    __shared__ unsigned short sh[64][68];    // [f/d][k]; 136B rows, 8B-aligned
    int gid = blockIdx.x;
    int t = threadIdx.x;

    if (gid >= NRTR) {
        int cg = gid - NRTR;
        int which = cg >> 12;                // 4096 blocks per matrix
        int local = cg & 4095;
        int e = local >> 9;                  // 512 tiles per expert
        int rem = local & 511;
        int rl = t >> 4, cl = (t & 15) * 4;  // load: 16 lanes/row, float4
        if (which < 2) {
            int ft = rem & 31, kg = rem >> 5;        // ft FASTEST: row streaming
            const float* S = ((which == 0) ? Win : Wsc) + (size_t)e * DIM * FF
                             + (size_t)(kg * 64) * FF + ft * 64;
            unsigned short* D = ((which == 0) ? wt_h : wt_s)
                                + (((size_t)e * 32 + ft) * 32 + kg * 2) * 2048;
#pragma unroll
            for (int p = 0; p < 4; ++p) {
                int k = p * 16 + rl;
                float4 v = *(const float4*)(S + (size_t)k * FF + cl);
                sh[cl + 0][k] = f2bf(v.x);
                sh[cl + 1][k] = f2bf(v.y);
                sh[cl + 2][k] = f2bf(v.z);
                sh[cl + 3][k] = f2bf(v.w);
            }
            __syncthreads();
            int r = t >> 2, c = t & 3;
#pragma unroll
            for (int p2 = 0; p2 < 2; ++p2) {         // two 4KB image blocks
                int ks = p2 * 32 + ((c ^ ((r >> 1) & 3)) * 8);
                uint2 lo = *(const uint2*)&sh[r][ks];
                uint2 hi = *(const uint2*)&sh[r][ks + 4];
                *(uint4*)(D + (size_t)p2 * 2048 + t * 8) =
                    make_uint4(lo.x, lo.y, hi.x, hi.y);
            }
        } else {
            int dg = rem & 15, kg = rem >> 4;        // dg FASTEST: row streaming
            const float* S = Wout + (size_t)e * DIM * FF
                             + (size_t)(kg * 64) * DIM + dg * 64;
            int dt = dg >> 1, o = (dg & 1) * 64;     // half of a 128d block
            unsigned short* D = wt_o + (((size_t)e * 8 + dt) * 64 + kg * 2) * 4096
                                + o * 32;
#pragma unroll
            for (int p = 0; p < 4; ++p) {
                int k = p * 16 + rl;
                float4 v = *(const float4*)(S + (size_t)k * DIM + cl);
                sh[cl + 0][k] = f2bf(v.x);
                sh[cl + 1][k] = f2bf(v.y);
                sh[cl + 2][k] = f2bf(v.z);
                sh[cl + 3][k] = f2bf(v.w);
            }
            __syncthreads();
            int r = t >> 2, c = t & 3;               // r is local d (o+r global)
#pragma unroll
            for (int p2 = 0; p2 < 2; ++p2) {
                int ks = p2 * 32 + ((c ^ ((r >> 1) & 3)) * 8);
                uint2 lo = *(const uint2*)&sh[r][ks];
                uint2 hi = *(const uint2*)&sh[r][ks + 4];
                *(uint4*)(D + (size_t)p2 * 4096 + t * 8) =
                    make_uint4(lo.x, lo.y, hi.x, hi.y);
            }
        }
        return;
    }

    // ------- router (+assign in mode 1), gid in [0, NRTR) -------
    int rblk = gid;
    int wave = t >> 6, lane = t & 63;
    int tok = rblk * 4 + wave;
    if (mode && rblk == 0 && t < NEXP) hdr[16 + t] = t * N_TOK;  // fixed bases

    float acc[NEXP];
#pragma unroll
    for (int e = 0; e < NEXP; ++e) acc[e] = 0.f;
    const float* xr = x + (size_t)tok * DIM;
    for (int d = lane; d < DIM; d += 64) {
        float xv = xr[d];
        const float* wr = Wg + d * NEXP;
        float4 w0 = *(const float4*)wr;          // vectorized gather: 2 loads
        float4 w1 = *(const float4*)(wr + 4);    // instead of 8 scalars
        acc[0] += xv * w0.x; acc[1] += xv * w0.y;
        acc[2] += xv * w0.z; acc[3] += xv * w0.w;
        acc[4] += xv * w1.x; acc[5] += xv * w1.y;
        acc[6] += xv * w1.z; acc[7] += xv * w1.w;
    }
#pragma unroll
    for (int off = 32; off > 0; off >>= 1) {
#pragma unroll
        for (int e = 0; e < NEXP; ++e) acc[e] += __shfl_down(acc[e], off);
    }
    int s0 = 0, s1 = 0;
    if (lane == 0) {
        int e0 = 0;
#pragma unroll
        for (int e = 1; e < NEXP; ++e) if (acc[e] > acc[e0]) e0 = e;
        int e1 = -1;
#pragma unroll
        for (int e = 0; e < NEXP; ++e) {
            if (e == e0) continue;
            if (e1 < 0 || acc[e] > acc[e1]) e1 = e;
        }
        float w0 = 1.f / (1.f + expf(acc[e1] - acc[e0]));
        tok_e[2 * tok] = e0; tok_e[2 * tok + 1] = e1;
        tok_w[2 * tok] = w0; tok_w[2 * tok + 1] = 1.f - w0;
        if (mode) {
            int p0 = atomicAdd(&hdr[e0], 1);
            int p1 = atomicAdd(&hdr[e1], 1);
            s0 = e0 * N_TOK + p0; s1 = e1 * N_TOK + p1;
            tok_slot[2 * tok] = s0; tok_slot[2 * tok + 1] = s1;
        } else {
            atomicAdd(&hdr[e0], 1);
            atomicAdd(&hdr[e1], 1);
        }
    }
    if (mode) {       // fused assign: gather this token's row -> both slabs
        s0 = __shfl(s0, 0); s1 = __shfl(s1, 0);
        const float4* xv4 = (const float4*)xr;
#pragma unroll
        for (int j = 0; j < 4; ++j) {
            float4 v = xv4[lane + j * 64];
            ushort4 b;
            b.x = f2bf(v.x); b.y = f2bf(v.y); b.z = f2bf(v.z); b.w = f2bf(v.w);
            ((ushort4*)(xg + (size_t)s0 * DIM))[lane + j * 64] = b;
            ((ushort4*)(xg + (size_t)s1 * DIM))[lane + j * 64] = b;
        }
    }
}

// ---------------- scan (compact mode only) ------------------------------------
__global__ void k_scan(int* hdr) {
    if (threadIdx.x == 0 && blockIdx.x == 0) {
        int s = 0;
        for (int e = 0; e < NEXP; ++e) {
            hdr[16 + e] = s;
            hdr[8 + e]  = s;
            s += hdr[e];
        }
        hdr[24] = s;
    }
}

// ---------------- assign (compact mode only) ----------------------------------
__global__ __launch_bounds__(256) void k_assign(const float* __restrict__ x,
        int* __restrict__ hdr, const int* __restrict__ tok_e,
        int* __restrict__ tok_slot, unsigned short* __restrict__ xg) {
    __shared__ int sh[2];
    int t = blockIdx.x;
    if (threadIdx.x == 0) {
        int e0 = tok_e[2 * t], e1 = tok_e[2 * t + 1];
        int p0 = atomicAdd(&hdr[8 + e0], 1);
        int p1 = atomicAdd(&hdr[8 + e1], 1);
        tok_slot[2 * t] = p0; tok_slot[2 * t + 1] = p1;
        sh[0] = p0; sh[1] = p1;
    }
    __syncthreads();
    int s0 = sh[0], s1 = sh[1];
    const float4* xr = (const float4*)(x + (size_t)t * DIM);
    float4 v = xr[threadIdx.x];
    ushort4 b;
    b.x = f2bf(v.x); b.y = f2bf(v.y); b.z = f2bf(v.z); b.w = f2bf(v.w);
    ((ushort4*)(xg + (size_t)s0 * DIM))[threadIdx.x] = b;
    ((ushort4*)(xg + (size_t)s1 * DIM))[threadIdx.x] = b;
}

// ---------------- expert dual-GEMM h & s + exact GELU -> inner (bf16) --------
// tile 128 x 64F, K-step 32, 4 waves 2x2, acc=64 VGPR -> 4 blocks/CU.
// Dbuf stage-ahead, ONE barrier/step.  B from blocked image (linear DMA src).
__global__ __launch_bounds__(256, 4) void k_expert_hs(
        const unsigned short* __restrict__ xg,
        const unsigned short* __restrict__ Wth,
        const unsigned short* __restrict__ Wts,
        const float* __restrict__ b_in, const float* __restrict__ b_sc,
        const int* __restrict__ hdr, unsigned short* __restrict__ inner) {
    int e = blockIdx.z;
    int cnt = hdr[e];
    int mtile = blockIdx.y;
    if (mtile * 128 >= cnt) return;
    int base = hdr[16 + e];
    int f0 = blockIdx.x * 64;

    __shared__ unsigned short As[2 * 128 * 32];  // dbuf [row][k] 64B rows
    __shared__ unsigned short Bh[2 * 64 * 32];
    __shared__ unsigned short Bs[2 * 64 * 32];

    int tid = threadIdx.x;
    int wave = tid >> 6, lane = tid & 63;
    int lr = lane & 15, lq = lane >> 4;
    int wm = (wave >> 1) * 64, wf = (wave & 1) * 32;

    f32x4 acch[4][2], accs[4][2];
#pragma unroll
    for (int mi = 0; mi < 4; ++mi)
#pragma unroll
        for (int fi = 0; fi < 2; ++fi) {
            acch[mi][fi] = (f32x4){0.f, 0.f, 0.f, 0.f};
            accs[mi][fi] = (f32x4){0.f, 0.f, 0.f, 0.f};
        }

    int swzc = (lane & 3) ^ ((lane >> 3) & 3);
    int goff = (lane >> 2) * DIM + swzc * 8;           // A: ushort units, ld=DIM
    int rdo = lr * 32 + (lq ^ ((lr >> 1) & 3)) * 8;    // swizzled read offset

    const unsigned short* Abase = xg  + (size_t)(base + mtile * 128) * DIM + goff;
    // blocked B: per (e,ft) panel is 32 sequential 2048-short blocks
    const unsigned short* Hp = Wth + (((size_t)e * 32 + (f0 >> 6)) * 32) * 2048
                               + wave * 512 + lane * 8;
    const unsigned short* Sp = Wts + (((size_t)e * 32 + (f0 >> 6)) * 32) * 2048
                               + wave * 512 + lane * 8;
    int pa0 = wave * 16, pa1 = 64 + wave * 16;
    int wb = wave * 512;

    GLOAD_LDS16(Abase + (size_t)pa0 * DIM, &As[pa0 * 32]);
    GLOAD_LDS16(Abase + (size_t)pa1 * DIM, &As[pa1 * 32]);
    GLOAD_LDS16(Hp, &Bh[wb]);
    GLOAD_LDS16(Sp, &Bs[wb]);
    __syncthreads();

    const int NSTEP = DIM / 32;
    for (int t = 0; t < NSTEP; ++t) {
        int coA = (t & 1) * (128 * 32), coB = (t & 1) * (64 * 32);
        if (t + 1 < NSTEP) {                 // stage next tile first (overlap)
            int noA = ((t & 1) ^ 1) * (128 * 32), noB = ((t & 1) ^ 1) * (64 * 32);
            int k1 = (t + 1) * 32;
            GLOAD_LDS16(Abase + (size_t)pa0 * DIM + k1, &As[noA + pa0 * 32]);
            GLOAD_LDS16(Abase + (size_t)pa1 * DIM + k1, &As[noA + pa1 * 32]);
            GLOAD_LDS16(Hp + (size_t)(t + 1) * 2048, &Bh[noB + wb]);
            GLOAD_LDS16(Sp + (size_t)(t + 1) * 2048, &Bs[noB + wb]);
        }

        short8 af[4], bhf[2], bsf[2];
#pragma unroll
        for (int mi = 0; mi < 4; ++mi)
            af[mi] = *(const short8*)&As[coA + (wm + mi * 16) * 32 + rdo];
#pragma unroll
        for (int fi = 0; fi < 2; ++fi) {
            bhf[fi] = *(const short8*)&Bh[coB + (wf + fi * 16) * 32 + rdo];
            bsf[fi] = *(const short8*)&Bs[coB + (wf + fi * 16) * 32 + rdo];
        }
#pragma unroll
        for (int mi = 0; mi < 4; ++mi)
#pragma unroll
            for (int fi = 0; fi < 2; ++fi) {
                acch[mi][fi] = __builtin_amdgcn_mfma_f32_16x16x32_bf16(
                    af[mi], bhf[fi], acch[mi][fi], 0, 0, 0);
                accs[mi][fi] = __builtin_amdgcn_mfma_f32_16x16x32_bf16(
                    af[mi], bsf[fi], accs[mi][fi], 0, 0, 0);
            }
        __syncthreads();   // readers done + next-tile DMA drained (vmcnt 0)
    }

#pragma unroll
    for (int fi = 0; fi < 2; ++fi) {
        int f = f0 + wf + fi * 16 + lr;
        float bi = b_in[e * FF + f];
        float bs2 = b_sc[e * FF + f];
#pragma unroll
        for (int mi = 0; mi < 4; ++mi) {
#pragma unroll
            for (int r = 0; r < 4; ++r) {
                int rl = wm + mi * 16 + lq * 4 + r;
                int grow = mtile * 128 + rl;
                if (grow < cnt) {
                    float h = acch[mi][fi][r] + bi;
                    float s = accs[mi][fi][r] + bs2;
                    float g = 0.5f * h * (1.f + erff(h * 0.70710678f));
                    inner[(size_t)(base + grow) * FF + f] = f2bf(g * s);
                }
            }
        }
    }
}

// ---------------- expert out-GEMM, split-K=2, fp16 partials -------------------
// tile 128 x 128D, 4 waves 2x2, acc=64 VGPR -> 4 blocks/CU.  Blocked B image.
__global__ __launch_bounds__(256, 4) void k_expert_out(
        const unsigned short* __restrict__ inner,
        const unsigned short* __restrict__ Wto,
        const int* __restrict__ hdr, half_t* __restrict__ pbuf, int pstride) {
    int e = blockIdx.z & 7;
    int ks = blockIdx.z >> 3;
    int cnt = hdr[e];
    int mtile = blockIdx.y;
    if (mtile * 128 >= cnt) return;
    int base = hdr[16 + e];
    int d0 = blockIdx.x * 128;

    __shared__ unsigned short As[2 * 128 * 32];  // dbuf [row][k]
    __shared__ unsigned short Bt[2 * 128 * 32];  // dbuf [d][k] image

    int tid = threadIdx.x;
    int wave = tid >> 6, lane = tid & 63;
    int lr = lane & 15, lq = lane >> 4;
    int wm = (wave >> 1) * 64, wn = (wave & 1) * 64;

    f32x4 acc[4][4];
#pragma unroll
    for (int mi = 0; mi < 4; ++mi)
#pragma unroll
        for (int ni = 0; ni < 4; ++ni) acc[mi][ni] = (f32x4){0.f, 0.f, 0.f, 0.f};

    int swzc = (lane & 3) ^ ((lane >> 3) & 3);
    int goff = (lane >> 2) * FF + swzc * 8;            // A: ld = FF
    int rdo = lr * 32 + (lq ^ ((lr >> 1) & 3)) * 8;

    const unsigned short* Abase = inner + (size_t)(base + mtile * 128) * FF + goff;
    // blocked B: per (e,dt) panel is 64 sequential 4096-short blocks; start at ks*32
    const unsigned short* Bp = Wto + ((((size_t)e * 8 + (d0 >> 7)) * 64 + (size_t)ks * 32)) * 4096
                               + wave * 512 + lane * 8;
    int pa0 = wave * 16, pa1 = 64 + wave * 16;
    int wb = wave * 512;

    int kbeg = ks * (FF / 2);

    GLOAD_LDS16(Abase + (size_t)pa0 * FF + kbeg, &As[pa0 * 32]);
    GLOAD_LDS16(Abase + (size_t)pa1 * FF + kbeg, &As[pa1 * 32]);
    GLOAD_LDS16(Bp, &Bt[wb]);
    GLOAD_LDS16(Bp + 2048, &Bt[2048 + wb]);
    __syncthreads();

    const int NSTEP = (FF / 2) / 32;
    for (int t = 0; t < NSTEP; ++t) {
        int co = (t & 1) * (128 * 32);
        if (t + 1 < NSTEP) {
            int no = ((t & 1) ^ 1) * (128 * 32);
            int k1 = kbeg + (t + 1) * 32;
            GLOAD_LDS16(Abase + (size_t)pa0 * FF + k1, &As[no + pa0 * 32]);
            GLOAD_LDS16(Abase + (size_t)pa1 * FF + k1, &As[no + pa1 * 32]);
            GLOAD_LDS16(Bp + (size_t)(t + 1) * 4096, &Bt[no + wb]);
            GLOAD_LDS16(Bp + (size_t)(t + 1) * 4096 + 2048, &Bt[no + 2048 + wb]);
        }

        short8 af[4], bfm[4];
#pragma unroll
        for (int mi = 0; mi < 4; ++mi)
            af[mi] = *(const short8*)&As[co + (wm + mi * 16) * 32 + rdo];
#pragma unroll
        for (int ni = 0; ni < 4; ++ni)
            bfm[ni] = *(const short8*)&Bt[co + (wn + ni * 16) * 32 + rdo];
#pragma unroll
        for (int mi = 0; mi < 4; ++mi)
#pragma unroll
            for (int ni = 0; ni < 4; ++ni)
                acc[mi][ni] = __builtin_amdgcn_mfma_f32_16x16x32_bf16(
                    af[mi], bfm[ni], acc[mi][ni], 0, 0, 0);
        __syncthreads();
    }

    half_t* P = pbuf + (size_t)ks * pstride * DIM;
#pragma unroll
    for (int ni = 0; ni < 4; ++ni) {
        int d = d0 + wn + ni * 16 + lr;
#pragma unroll
        for (int mi = 0; mi < 4; ++mi) {
#pragma unroll
            for (int r = 0; r < 4; ++r) {
                int rl = wm + mi * 16 + lq * 4 + r;
                int grow = mtile * 128 + rl;
                if (grow < cnt)
                    P[(size_t)(base + grow) * DIM + d] = (half_t)acc[mi][ni][r];
            }
        }
    }
}

// ---------------- combine: out = w0*(p0+p1+b[e0]) + w1*(...) ------------------
__global__ __launch_bounds__(256) void k_combine(const half_t* __restrict__ pbuf,
        const int* __restrict__ tok_slot, const int* __restrict__ tok_e,
        const float* __restrict__ tok_w, const float* __restrict__ b_out,
        float* __restrict__ out, int pstride) {
    int t = blockIdx.x;
    int d = threadIdx.x * 4;
    int s0 = tok_slot[2 * t], s1 = tok_slot[2 * t + 1];
    int e0 = tok_e[2 * t], e1 = tok_e[2 * t + 1];
    float w0 = tok_w[2 * t], w1 = tok_w[2 * t + 1];
    const half_t* pA = pbuf;
    const half_t* pB = pbuf + (size_t)pstride * DIM;
    h16x4 a0 = *(const h16x4*)&pA[(size_t)s0 * DIM + d];
    h16x4 a1 = *(const h16x4*)&pB[(size_t)s0 * DIM + d];
    h16x4 c0 = *(const h16x4*)&pA[(size_t)s1 * DIM + d];
    h16x4 c1 = *(const h16x4*)&pB[(size_t)s1 * DIM + d];
    float4 b0 = *(const float4*)&b_out[e0 * DIM + d];
    float4 b1 = *(const float4*)&b_out[e1 * DIM + d];
    float4 r;
    r.x = w0 * ((float)a0.x + (float)a1.x + b0.x) + w1 * ((float)c0.x + (float)c1.x + b1.x);
    r.y = w0 * ((float)a0.y + (float)a1.y + b0.y) + w1 * ((float)c0.y + (float)c1.y + b1.y);
    r.z = w0 * ((float)a0.z + (float)a1.z + b0.z) + w1 * ((float)c0.z + (float)c1.z + b1.z);
    r.w = w0 * ((float)a0.w + (float)a1.w + b0.w) + w1 * ((float)c0.w + (float)c1.w + b1.w);
    *(float4*)&out[(size_t)t * DIM + d] = r;
}

extern "C" void kernel_launch(void* const* d_in, const int* in_sizes, int n_in,
                              void* d_out, int out_size, void* d_ws, size_t ws_size,
                              hipStream_t stream) {
    (void)in_sizes; (void)n_in; (void)out_size;
    const float* x    = (const float*)d_in[0];
    const float* Wg   = (const float*)d_in[1];
    const float* Win  = (const float*)d_in[2];
    const float* b_in = (const float*)d_in[3];
    const float* Wsc  = (const float*)d_in[4];
    const float* b_sc = (const float*)d_in[5];
    const float* Wout = (const float*)d_in[6];
    const float* b_out= (const float*)d_in[7];
    float* out = (float*)d_out;

    char* ws = (char*)d_ws;
    int*   hdr      = (int*)ws;
    int*   tok_e    = (int*)(ws + 256);
    float* tok_w    = (float*)(ws + 16640);
    int*   tok_slot = (int*)(ws + 33024);

    // big mode: fixed per-expert slabs (base_e = e*2048) -> no scan/assign
    const size_t BIG_NEED = 65792ULL + (32ULL + 64 + 64 + 96) * 1024 * 1024;
    int big = (ws_size >= BIG_NEED) ? 1 : 0;

    unsigned short *xg, *inner, *wt_h, *wt_s, *wt_o;
    half_t* pbuf;
    int slab;
    if (big) {
        xg    = (unsigned short*)(ws + 65792);                       // 32 MB
        inner = (unsigned short*)(ws + 65792 + 33554432);            // 64 MB
        pbuf  = (half_t*)(ws + 65792 + 33554432 + 67108864);         // 64 MB
        wt_h  = (unsigned short*)(ws + 65792 + 33554432 + 67108864 + 67108864);
        wt_s  = wt_h + (size_t)NEXP * FF * DIM;                      // +32 MB
        wt_o  = wt_s + (size_t)NEXP * FF * DIM;                      // +32 MB
        slab  = NEXP * N_TOK;                                        // 16384
    } else {
        xg    = (unsigned short*)(ws + 65792);                       // 8 MB
        inner = (unsigned short*)(ws + 65792 + 8388608);             // 16 MB
        pbuf  = (half_t*)(ws + 65792 + 8388608 + 16777216);          // 16 MB
        wt_h  = (unsigned short*)(ws + 65792 + 8388608 + 16777216 + 16777216);
        wt_s  = wt_h + (size_t)NEXP * FF * DIM;                      // +32 MB
        wt_o  = wt_s + (size_t)NEXP * FF * DIM;                      // +32 MB
        slab  = NSLOT;                                               // 4096
    }

    hipMemsetAsync(hdr, 0, 256, stream);
    k_prep<<<dim3(NRTR + NCVT), dim3(256), 0, stream>>>(
        x, Wg, Win, Wsc, Wout, wt_h, wt_s, wt_o,
        hdr, tok_e, tok_w, tok_slot, xg, big);
    if (!big) {
        k_scan<<<dim3(1), dim3(64), 0, stream>>>(hdr);
        k_assign<<<dim3(N_TOK), dim3(256), 0, stream>>>(x, hdr, tok_e, tok_slot, xg);
    }
    k_expert_hs<<<dim3(FF / 64, 16, NEXP), dim3(256), 0, stream>>>(
        xg, wt_h, wt_s, b_in, b_sc, hdr, inner);
    k_expert_out<<<dim3(DIM / 128, 16, NEXP * 2), dim3(256), 0, stream>>>(
        inner, wt_o, hdr, pbuf, slab);
    k_combine<<<dim3(N_TOK), dim3(256), 0, stream>>>(
        pbuf, tok_slot, tok_e, tok_w, b_out, out, slab);
}

// Round 11
// 412.933 us; speedup vs baseline: 1.0453x; 1.0019x over previous
//
#include <hip/hip_runtime.h>
#include <hip/hip_bf16.h>
#include <math.h>

#define N_TOK 2048
#define DIM   1024
#define FF    2048
#define NEXP  8
#define NSLOT (N_TOK * 2)
#define NRTR  (N_TOK / 4)   // 512 router blocks, FIRST in grid (latency-hidden)
#define NCVT  8192          // wt_h + wt_s only: 2 matrices x 8 experts x 512 tiles

typedef __attribute__((ext_vector_type(8))) short short8;
typedef __attribute__((ext_vector_type(4))) float f32x4;
typedef _Float16 half_t;
typedef __attribute__((ext_vector_type(4))) _Float16 h16x4;

__device__ __forceinline__ unsigned short f2bf(float f) {
    unsigned int u = __float_as_uint(f);
    u += 0x7FFFu + ((u >> 16) & 1u);   // round-to-nearest-even
    return (unsigned short)(u >> 16);
}

// async global->LDS 16B: LDS dst is wave-uniform base + lane*16
#define GLOAD_LDS16(g, l) \
    __builtin_amdgcn_global_load_lds((const __attribute__((address_space(1))) unsigned int*)(g), \
                                     (__attribute__((address_space(3))) unsigned int*)(l), 16, 0, 0)

// ---------------- prep: router (+assign) FIRST, then wt_h/wt_s cvt ------------
// wt_o conversion has moved into k_expert_hs's grid (it isn't needed until
// k_expert_out) -- takes 1/3 of the cvt traffic off the critical path.
__global__ __launch_bounds__(256) void k_prep(
        const float* __restrict__ x, const float* __restrict__ Wg,
        const float* __restrict__ Win, const float* __restrict__ Wsc,
        unsigned short* __restrict__ wt_h, unsigned short* __restrict__ wt_s,
        int* __restrict__ hdr, int* __restrict__ tok_e,
        float* __restrict__ tok_w, int* __restrict__ tok_slot,
        unsigned short* __restrict__ xg, int mode) {
    __shared__ unsigned short sh[64][68];    // [f][k]; 136B rows, 8B-aligned
    int gid = blockIdx.x;
    int t = threadIdx.x;

    if (gid >= NRTR) {
        int cg = gid - NRTR;
        int which = cg >> 12;                // 4096 blocks per matrix (0 or 1)
        int local = cg & 4095;
        int e = local >> 9;                  // 512 tiles per expert
        int rem = local & 511;
        int rl = t >> 4, cl = (t & 15) * 4;  // load: 16 lanes/row, float4
        int ft = rem & 31, kg = rem >> 5;    // ft FASTEST: row streaming
        const float* S = ((which == 0) ? Win : Wsc) + (size_t)e * DIM * FF
                         + (size_t)(kg * 64) * FF + ft * 64;
        unsigned short* D = ((which == 0) ? wt_h : wt_s)
                            + (((size_t)e * 32 + ft) * 32 + kg * 2) * 2048;
#pragma unroll
        for (int p = 0; p < 4; ++p) {
            int k = p * 16 + rl;
            float4 v = *(const float4*)(S + (size_t)k * FF + cl);
            sh[cl + 0][k] = f2bf(v.x);
            sh[cl + 1][k] = f2bf(v.y);
            sh[cl + 2][k] = f2bf(v.z);
            sh[cl + 3][k] = f2bf(v.w);
        }
        __syncthreads();
        int r = t >> 2, c = t & 3;
#pragma unroll
        for (int p2 = 0; p2 < 2; ++p2) {     // two 4KB image blocks
            int ks = p2 * 32 + ((c ^ ((r >> 1) & 3)) * 8);
            uint2 lo = *(const uint2*)&sh[r][ks];
            uint2 hi = *(const uint2*)&sh[r][ks + 4];
            *(uint4*)(D + (size_t)p2 * 2048 + t * 8) =
                make_uint4(lo.x, lo.y, hi.x, hi.y);
        }
        return;
    }

    // ------- router (+assign in mode 1), gid in [0, NRTR) -------
    int rblk = gid;
    int wave = t >> 6, lane = t & 63;
    int tok = rblk * 4 + wave;
    if (mode && rblk == 0 && t < NEXP) hdr[16 + t] = t * N_TOK;  // fixed bases

    float acc[NEXP];
#pragma unroll
    for (int e = 0; e < NEXP; ++e) acc[e] = 0.f;
    const float* xr = x + (size_t)tok * DIM;
    for (int d = lane; d < DIM; d += 64) {
        float xv = xr[d];
        const float* wr = Wg + d * NEXP;
        float4 w0 = *(const float4*)wr;          // vectorized gather
        float4 w1 = *(const float4*)(wr + 4);
        acc[0] += xv * w0.x; acc[1] += xv * w0.y;
        acc[2] += xv * w0.z; acc[3] += xv * w0.w;
        acc[4] += xv * w1.x; acc[5] += xv * w1.y;
        acc[6] += xv * w1.z; acc[7] += xv * w1.w;
    }
#pragma unroll
    for (int off = 32; off > 0; off >>= 1) {
#pragma unroll
        for (int e = 0; e < NEXP; ++e) acc[e] += __shfl_down(acc[e], off);
    }
    int s0 = 0, s1 = 0;
    if (lane == 0) {
        int e0 = 0;
#pragma unroll
        for (int e = 1; e < NEXP; ++e) if (acc[e] > acc[e0]) e0 = e;
        int e1 = -1;
#pragma unroll
        for (int e = 0; e < NEXP; ++e) {
            if (e == e0) continue;
            if (e1 < 0 || acc[e] > acc[e1]) e1 = e;
        }
        float w0 = 1.f / (1.f + expf(acc[e1] - acc[e0]));
        tok_e[2 * tok] = e0; tok_e[2 * tok + 1] = e1;
        tok_w[2 * tok] = w0; tok_w[2 * tok + 1] = 1.f - w0;
        if (mode) {
            int p0 = atomicAdd(&hdr[e0], 1);
            int p1 = atomicAdd(&hdr[e1], 1);
            s0 = e0 * N_TOK + p0; s1 = e1 * N_TOK + p1;
            tok_slot[2 * tok] = s0; tok_slot[2 * tok + 1] = s1;
        } else {
            atomicAdd(&hdr[e0], 1);
            atomicAdd(&hdr[e1], 1);
        }
    }
    if (mode) {       // fused assign: gather this token's row -> both slabs
        s0 = __shfl(s0, 0); s1 = __shfl(s1, 0);
        const float4* xv4 = (const float4*)xr;
#pragma unroll
        for (int j = 0; j < 4; ++j) {
            float4 v = xv4[lane + j * 64];
            ushort4 b;
            b.x = f2bf(v.x); b.y = f2bf(v.y); b.z = f2bf(v.z); b.w = f2bf(v.w);
            ((ushort4*)(xg + (size_t)s0 * DIM))[lane + j * 64] = b;
            ((ushort4*)(xg + (size_t)s1 * DIM))[lane + j * 64] = b;
        }
    }
}

// ---------------- scan (compact mode only) ------------------------------------
__global__ void k_scan(int* hdr) {
    if (threadIdx.x == 0 && blockIdx.x == 0) {
        int s = 0;
        for (int e = 0; e < NEXP; ++e) {
            hdr[16 + e] = s;
            hdr[8 + e]  = s;
            s += hdr[e];
        }
        hdr[24] = s;
    }
}

// ---------------- assign (compact mode only) ----------------------------------
__global__ __launch_bounds__(256) void k_assign(const float* __restrict__ x,
        int* __restrict__ hdr, const int* __restrict__ tok_e,
        int* __restrict__ tok_slot, unsigned short* __restrict__ xg) {
    __shared__ int sh[2];
    int t = blockIdx.x;
    if (threadIdx.x == 0) {
        int e0 = tok_e[2 * t], e1 = tok_e[2 * t + 1];
        int p0 = atomicAdd(&hdr[8 + e0], 1);
        int p1 = atomicAdd(&hdr[8 + e1], 1);
        tok_slot[2 * t] = p0; tok_slot[2 * t + 1] = p1;
        sh[0] = p0; sh[1] = p1;
    }
    __syncthreads();
    int s0 = sh[0], s1 = sh[1];
    const float4* xr = (const float4*)(x + (size_t)t * DIM);
    float4 v = xr[threadIdx.x];
    ushort4 b;
    b.x = f2bf(v.x); b.y = f2bf(v.y); b.z = f2bf(v.z); b.w = f2bf(v.w);
    ((ushort4*)(xg + (size_t)s0 * DIM))[threadIdx.x] = b;
    ((ushort4*)(xg + (size_t)s1 * DIM))[threadIdx.x] = b;
}

// ---------------- expert dual-GEMM h & s + GELU  (+ embedded wt_o cvt) -------
// grid (32, 16, 16): z<8 -> wt_o cvt blocks (dispatch FIRST, stream under the
// GEMM); z>=8 -> GEMM for expert z-8.  GEMM: tile 128x64F, K-step 32, dbuf
// stage-ahead, blocked pre-swizzled B image, acc=64 VGPR -> 4 blocks/CU.
__global__ __launch_bounds__(256, 4) void k_expert_hs(
        const unsigned short* __restrict__ xg,
        const unsigned short* __restrict__ Wth,
        const unsigned short* __restrict__ Wts,
        const float* __restrict__ b_in, const float* __restrict__ b_sc,
        const int* __restrict__ hdr, unsigned short* __restrict__ inner,
        const float* __restrict__ Wout, unsigned short* __restrict__ wt_o) {
    __shared__ unsigned short As[2 * 128 * 32];  // GEMM: dbuf A | cvt: scratch
    __shared__ unsigned short Bh[2 * 64 * 32];
    __shared__ unsigned short Bs[2 * 64 * 32];
    int tid = threadIdx.x;

    if (blockIdx.z < 8) {
        // ---- wt_o cvt block (4096 total): [E][F][D] f32 -> blocked bf16 image
        unsigned short (*sh)[68] = (unsigned short(*)[68])As;  // 64x68 scratch
        int cg = blockIdx.z * 512 + blockIdx.y * 32 + blockIdx.x;
        int e = cg >> 9, rem = cg & 511;
        int dg = rem & 15, kg = rem >> 4;            // dg FASTEST: row streaming
        const float* S = Wout + (size_t)e * DIM * FF
                         + (size_t)(kg * 64) * DIM + dg * 64;
        int dt = dg >> 1, o = (dg & 1) * 64;         // half of a 128d block
        unsigned short* D = wt_o + (((size_t)e * 8 + dt) * 64 + kg * 2) * 4096
                            + o * 32;
        int rl = tid >> 4, cl = (tid & 15) * 4;
#pragma unroll
        for (int p = 0; p < 4; ++p) {
            int k = p * 16 + rl;
            float4 v = *(const float4*)(S + (size_t)k * DIM + cl);
            sh[cl + 0][k] = f2bf(v.x);
            sh[cl + 1][k] = f2bf(v.y);
            sh[cl + 2][k] = f2bf(v.z);
            sh[cl + 3][k] = f2bf(v.w);
        }
        __syncthreads();
        int r = tid >> 2, c = tid & 3;
#pragma unroll
        for (int p2 = 0; p2 < 2; ++p2) {
            int ks = p2 * 32 + ((c ^ ((r >> 1) & 3)) * 8);
            uint2 lo = *(const uint2*)&sh[r][ks];
            uint2 hi = *(const uint2*)&sh[r][ks + 4];
            *(uint4*)(D + (size_t)p2 * 4096 + tid * 8) =
                make_uint4(lo.x, lo.y, hi.x, hi.y);
        }
        return;
    }

    // ---- GEMM block
    int e = blockIdx.z - 8;
    int cnt = hdr[e];
    int mtile = blockIdx.y;
    if (mtile * 128 >= cnt) return;
    int base = hdr[16 + e];
    int f0 = blockIdx.x * 64;

    int wave = tid >> 6, lane = tid & 63;
    int lr = lane & 15, lq = lane >> 4;
    int wm = (wave >> 1) * 64, wf = (wave & 1) * 32;

    f32x4 acch[4][2], accs[4][2];
#pragma unroll
    for (int mi = 0; mi < 4; ++mi)
#pragma unroll
        for (int fi = 0; fi < 2; ++fi) {
            acch[mi][fi] = (f32x4){0.f, 0.f, 0.f, 0.f};
            accs[mi][fi] = (f32x4){0.f, 0.f, 0.f, 0.f};
        }

    int swzc = (lane & 3) ^ ((lane >> 3) & 3);
    int goff = (lane >> 2) * DIM + swzc * 8;           // A: ushort units, ld=DIM
    int rdo = lr * 32 + (lq ^ ((lr >> 1) & 3)) * 8;    // swizzled read offset

    const unsigned short* Abase = xg  + (size_t)(base + mtile * 128) * DIM + goff;
    // blocked B: per (e,ft) panel is 32 sequential 2048-short blocks
    const unsigned short* Hp = Wth + (((size_t)e * 32 + (f0 >> 6)) * 32) * 2048
                               + wave * 512 + lane * 8;
    const unsigned short* Sp = Wts + (((size_t)e * 32 + (f0 >> 6)) * 32) * 2048
                               + wave * 512 + lane * 8;
    int pa0 = wave * 16, pa1 = 64 + wave * 16;
    int wb = wave * 512;

    GLOAD_LDS16(Abase + (size_t)pa0 * DIM, &As[pa0 * 32]);
    GLOAD_LDS16(Abase + (size_t)pa1 * DIM, &As[pa1 * 32]);
    GLOAD_LDS16(Hp, &Bh[wb]);
    GLOAD_LDS16(Sp, &Bs[wb]);
    __syncthreads();

    const int NSTEP = DIM / 32;
    for (int t = 0; t < NSTEP; ++t) {
        int coA = (t & 1) * (128 * 32), coB = (t & 1) * (64 * 32);
        if (t + 1 < NSTEP) {                 // stage next tile first (overlap)
            int noA = ((t & 1) ^ 1) * (128 * 32), noB = ((t & 1) ^ 1) * (64 * 32);
            int k1 = (t + 1) * 32;
            GLOAD_LDS16(Abase + (size_t)pa0 * DIM + k1, &As[noA + pa0 * 32]);
            GLOAD_LDS16(Abase + (size_t)pa1 * DIM + k1, &As[noA + pa1 * 32]);
            GLOAD_LDS16(Hp + (size_t)(t + 1) * 2048, &Bh[noB + wb]);
            GLOAD_LDS16(Sp + (size_t)(t + 1) * 2048, &Bs[noB + wb]);
        }

        short8 af[4], bhf[2], bsf[2];
#pragma unroll
        for (int mi = 0; mi < 4; ++mi)
            af[mi] = *(const short8*)&As[coA + (wm + mi * 16) * 32 + rdo];
#pragma unroll
        for (int fi = 0; fi < 2; ++fi) {
            bhf[fi] = *(const short8*)&Bh[coB + (wf + fi * 16) * 32 + rdo];
            bsf[fi] = *(const short8*)&Bs[coB + (wf + fi * 16) * 32 + rdo];
        }
#pragma unroll
        for (int mi = 0; mi < 4; ++mi)
#pragma unroll
            for (int fi = 0; fi < 2; ++fi) {
                acch[mi][fi] = __builtin_amdgcn_mfma_f32_16x16x32_bf16(
                    af[mi], bhf[fi], acch[mi][fi], 0, 0, 0);
                accs[mi][fi] = __builtin_amdgcn_mfma_f32_16x16x32_bf16(
                    af[mi], bsf[fi], accs[mi][fi], 0, 0, 0);
            }
        __syncthreads();   // readers done + next-tile DMA drained (vmcnt 0)
    }

#pragma unroll
    for (int fi = 0; fi < 2; ++fi) {
        int f = f0 + wf + fi * 16 + lr;
        float bi = b_in[e * FF + f];
        float bs2 = b_sc[e * FF + f];
#pragma unroll
        for (int mi = 0; mi < 4; ++mi) {
#pragma unroll
            for (int r = 0; r < 4; ++r) {
                int rl = wm + mi * 16 + lq * 4 + r;
                int grow = mtile * 128 + rl;
                if (grow < cnt) {
                    float h = acch[mi][fi][r] + bi;
                    float s = accs[mi][fi][r] + bs2;
                    float g = 0.5f * h * (1.f + erff(h * 0.70710678f));
                    inner[(size_t)(base + grow) * FF + f] = f2bf(g * s);
                }
            }
        }
    }
}

// ---------------- expert out-GEMM, split-K=2, fp16 partials -------------------
// tile 128 x 128D, 4 waves 2x2, acc=64 VGPR -> 4 blocks/CU.  Blocked B image.
__global__ __launch_bounds__(256, 4) void k_expert_out(
        const unsigned short* __restrict__ inner,
        const unsigned short* __restrict__ Wto,
        const int* __restrict__ hdr, half_t* __restrict__ pbuf, int pstride) {
    int e = blockIdx.z & 7;
    int ks = blockIdx.z >> 3;
    int cnt = hdr[e];
    int mtile = blockIdx.y;
    if (mtile * 128 >= cnt) return;
    int base = hdr[16 + e];
    int d0 = blockIdx.x * 128;

    __shared__ unsigned short As[2 * 128 * 32];  // dbuf [row][k]
    __shared__ unsigned short Bt[2 * 128 * 32];  // dbuf [d][k] image

    int tid = threadIdx.x;
    int wave = tid >> 6, lane = tid & 63;
    int lr = lane & 15, lq = lane >> 4;
    int wm = (wave >> 1) * 64, wn = (wave & 1) * 64;

    f32x4 acc[4][4];
#pragma unroll
    for (int mi = 0; mi < 4; ++mi)
#pragma unroll
        for (int ni = 0; ni < 4; ++ni) acc[mi][ni] = (f32x4){0.f, 0.f, 0.f, 0.f};

    int swzc = (lane & 3) ^ ((lane >> 3) & 3);
    int goff = (lane >> 2) * FF + swzc * 8;            // A: ld = FF
    int rdo = lr * 32 + (lq ^ ((lr >> 1) & 3)) * 8;

    const unsigned short* Abase = inner + (size_t)(base + mtile * 128) * FF + goff;
    // blocked B: per (e,dt) panel is 64 sequential 4096-short blocks; start at ks*32
    const unsigned short* Bp = Wto + ((((size_t)e * 8 + (d0 >> 7)) * 64 + (size_t)ks * 32)) * 4096
                               + wave * 512 + lane * 8;
    int pa0 = wave * 16, pa1 = 64 + wave * 16;
    int wb = wave * 512;

    int kbeg = ks * (FF / 2);

    GLOAD_LDS16(Abase + (size_t)pa0 * FF + kbeg, &As[pa0 * 32]);
    GLOAD_LDS16(Abase + (size_t)pa1 * FF + kbeg, &As[pa1 * 32]);
    GLOAD_LDS16(Bp, &Bt[wb]);
    GLOAD_LDS16(Bp + 2048, &Bt[2048 + wb]);
    __syncthreads();

    const int NSTEP = (FF / 2) / 32;
    for (int t = 0; t < NSTEP; ++t) {
        int co = (t & 1) * (128 * 32);
        if (t + 1 < NSTEP) {
            int no = ((t & 1) ^ 1) * (128 * 32);
            int k1 = kbeg + (t + 1) * 32;
            GLOAD_LDS16(Abase + (size_t)pa0 * FF + k1, &As[no + pa0 * 32]);
            GLOAD_LDS16(Abase + (size_t)pa1 * FF + k1, &As[no + pa1 * 32]);
            GLOAD_LDS16(Bp + (size_t)(t + 1) * 4096, &Bt[no + wb]);
            GLOAD_LDS16(Bp + (size_t)(t + 1) * 4096 + 2048, &Bt[no + 2048 + wb]);
        }

        short8 af[4], bfm[4];
#pragma unroll
        for (int mi = 0; mi < 4; ++mi)
            af[mi] = *(const short8*)&As[co + (wm + mi * 16) * 32 + rdo];
#pragma unroll
        for (int ni = 0; ni < 4; ++ni)
            bfm[ni] = *(const short8*)&Bt[co + (wn + ni * 16) * 32 + rdo];
#pragma unroll
        for (int mi = 0; mi < 4; ++mi)
#pragma unroll
            for (int ni = 0; ni < 4; ++ni)
                acc[mi][ni] = __builtin_amdgcn_mfma_f32_16x16x32_bf16(
                    af[mi], bfm[ni], acc[mi][ni], 0, 0, 0);
        __syncthreads();
    }

    half_t* P = pbuf + (size_t)ks * pstride * DIM;
#pragma unroll
    for (int ni = 0; ni < 4; ++ni) {
        int d = d0 + wn + ni * 16 + lr;
#pragma unroll
        for (int mi = 0; mi < 4; ++mi) {
#pragma unroll
            for (int r = 0; r < 4; ++r) {
                int rl = wm + mi * 16 + lq * 4 + r;
                int grow = mtile * 128 + rl;
                if (grow < cnt)
                    P[(size_t)(base + grow) * DIM + d] = (half_t)acc[mi][ni][r];
            }
        }
    }
}

// ---------------- combine: out = w0*(p0+p1+b[e0]) + w1*(...) ------------------
__global__ __launch_bounds__(256) void k_combine(const half_t* __restrict__ pbuf,
        const int* __restrict__ tok_slot, const int* __restrict__ tok_e,
        const float* __restrict__ tok_w, const float* __restrict__ b_out,
        float* __restrict__ out, int pstride) {
    int t = blockIdx.x;
    int d = threadIdx.x * 4;
    int s0 = tok_slot[2 * t], s1 = tok_slot[2 * t + 1];
    int e0 = tok_e[2 * t], e1 = tok_e[2 * t + 1];
    float w0 = tok_w[2 * t], w1 = tok_w[2 * t + 1];
    const half_t* pA = pbuf;
    const half_t* pB = pbuf + (size_t)pstride * DIM;
    h16x4 a0 = *(const h16x4*)&pA[(size_t)s0 * DIM + d];
    h16x4 a1 = *(const h16x4*)&pB[(size_t)s0 * DIM + d];
    h16x4 c0 = *(const h16x4*)&pA[(size_t)s1 * DIM + d];
    h16x4 c1 = *(const h16x4*)&pB[(size_t)s1 * DIM + d];
    float4 b0 = *(const float4*)&b_out[e0 * DIM + d];
    float4 b1 = *(const float4*)&b_out[e1 * DIM + d];
    float4 r;
    r.x = w0 * ((float)a0.x + (float)a1.x + b0.x) + w1 * ((float)c0.x + (float)c1.x + b1.x);
    r.y = w0 * ((float)a0.y + (float)a1.y + b0.y) + w1 * ((float)c0.y + (float)c1.y + b1.y);
    r.z = w0 * ((float)a0.z + (float)a1.z + b0.z) + w1 * ((float)c0.z + (float)c1.z + b1.z);
    r.w = w0 * ((float)a0.w + (float)a1.w + b0.w) + w1 * ((float)c0.w + (float)c1.w + b1.w);
    *(float4*)&out[(size_t)t * DIM + d] = r;
}

extern "C" void kernel_launch(void* const* d_in, const int* in_sizes, int n_in,
                              void* d_out, int out_size, void* d_ws, size_t ws_size,
                              hipStream_t stream) {
    (void)in_sizes; (void)n_in; (void)out_size;
    const float* x    = (const float*)d_in[0];
    const float* Wg   = (const float*)d_in[1];
    const float* Win  = (const float*)d_in[2];
    const float* b_in = (const float*)d_in[3];
    const float* Wsc  = (const float*)d_in[4];
    const float* b_sc = (const float*)d_in[5];
    const float* Wout = (const float*)d_in[6];
    const float* b_out= (const float*)d_in[7];
    float* out = (float*)d_out;

    char* ws = (char*)d_ws;
    int*   hdr      = (int*)ws;
    int*   tok_e    = (int*)(ws + 256);
    float* tok_w    = (float*)(ws + 16640);
    int*   tok_slot = (int*)(ws + 33024);

    // big mode: fixed per-expert slabs (base_e = e*2048) -> no scan/assign
    const size_t BIG_NEED = 65792ULL + (32ULL + 64 + 64 + 96) * 1024 * 1024;
    int big = (ws_size >= BIG_NEED) ? 1 : 0;

    unsigned short *xg, *inner, *wt_h, *wt_s, *wt_o;
    half_t* pbuf;
    int slab;
    if (big) {
        xg    = (unsigned short*)(ws + 65792);                       // 32 MB
        inner = (unsigned short*)(ws + 65792 + 33554432);            // 64 MB
        pbuf  = (half_t*)(ws + 65792 + 33554432 + 67108864);         // 64 MB
        wt_h  = (unsigned short*)(ws + 65792 + 33554432 + 67108864 + 67108864);
        wt_s  = wt_h + (size_t)NEXP * FF * DIM;                      // +32 MB
        wt_o  = wt_s + (size_t)NEXP * FF * DIM;                      // +32 MB
        slab  = NEXP * N_TOK;                                        // 16384
    } else {
        xg    = (unsigned short*)(ws + 65792);                       // 8 MB
        inner = (unsigned short*)(ws + 65792 + 8388608);             // 16 MB
        pbuf  = (half_t*)(ws + 65792 + 8388608 + 16777216);          // 16 MB
        wt_h  = (unsigned short*)(ws + 65792 + 8388608 + 16777216 + 16777216);
        wt_s  = wt_h + (size_t)NEXP * FF * DIM;                      // +32 MB
        wt_o  = wt_s + (size_t)NEXP * FF * DIM;                      // +32 MB
        slab  = NSLOT;                                               // 4096
    }

    hipMemsetAsync(hdr, 0, 256, stream);
    k_prep<<<dim3(NRTR + NCVT), dim3(256), 0, stream>>>(
        x, Wg, Win, Wsc, wt_h, wt_s,
        hdr, tok_e, tok_w, tok_slot, xg, big);
    if (!big) {
        k_scan<<<dim3(1), dim3(64), 0, stream>>>(hdr);
        k_assign<<<dim3(N_TOK), dim3(256), 0, stream>>>(x, hdr, tok_e, tok_slot, xg);
    }
    // hs GEMM (z=8..15) + embedded wt_o cvt (z=0..7, dispatched first)
    k_expert_hs<<<dim3(FF / 64, 16, 16), dim3(256), 0, stream>>>(
        xg, wt_h, wt_s, b_in, b_sc, hdr, inner, Wout, wt_o);
    k_expert_out<<<dim3(DIM / 128, 16, NEXP * 2), dim3(256), 0, stream>>>(
        inner, wt_o, hdr, pbuf, slab);
    k_combine<<<dim3(N_TOK), dim3(256), 0, stream>>>(
        pbuf, tok_slot, tok_e, tok_w, b_out, out, slab);
}